// Round 8
// baseline (52394.751 us; speedup 1.0000x reference)
//
#include <hip/hip_runtime.h>
#include <hip/hip_bf16.h>

// ---------------------------------------------------------------------------
// Bidirectional 2-layer GRU encoder, B=64, S=512, D=H=512.
// R8 = R7's proven math/protocol with the exchange consumption rebuilt:
//   - NO LDS staging: MFMA A-fragments are loaded DIRECTLY from the published
//     global buffers as batched u64 system-scope atomic loads (proven
//     mechanism), one RTT per hop, zero LDS bank conflicts.
//   - wave-0-only ballot spin (no barriers in poll loop), s_sleep(2).
// Math identical to R4..R7 (absmax 2.441e-4).
// ---------------------------------------------------------------------------

typedef short bf16x8 __attribute__((ext_vector_type(8)));
typedef float f32x4  __attribute__((ext_vector_type(4)));
typedef unsigned short u16x8 __attribute__((ext_vector_type(8)));
typedef unsigned long long u64;

#define SBH 16777216ull   // S*B*H = 512*64*512
#define NWG_DIR 16

__device__ __forceinline__ unsigned short f2b(float f){
  __hip_bfloat16 h = __float2bfloat16(f);
  unsigned short u; __builtin_memcpy(&u, &h, 2); return u;
}
__device__ __forceinline__ float b2f(unsigned short u){
  __hip_bfloat16 h; __builtin_memcpy(&h, &u, 2); return __bfloat162float(h);
}

__device__ __forceinline__ u64 ld_sys_u64(const u64* p){
  return __hip_atomic_load(p, __ATOMIC_RELAXED, __HIP_MEMORY_SCOPE_SYSTEM);
}
__device__ __forceinline__ void st_sys_u64(u64* p, u64 v){
  __hip_atomic_store(p, v, __ATOMIC_RELAXED, __HIP_MEMORY_SCOPE_SYSTEM);
}
__device__ __forceinline__ void st_sys_u32(unsigned int* p, unsigned int v){
  __hip_atomic_store(p, v, __ATOMIC_RELAXED, __HIP_MEMORY_SCOPE_SYSTEM);
}
__device__ __forceinline__ int ld_sys_i32(const int* p){
  return __hip_atomic_load(p, __ATOMIC_RELAXED, __HIP_MEMORY_SCOPE_SYSTEM);
}
__device__ __forceinline__ void st_sys_i32(int* p, int v){
  __hip_atomic_store(p, v, __ATOMIC_RELAXED, __HIP_MEMORY_SCOPE_SYSTEM);
}
__device__ __forceinline__ void vm0(){
  asm volatile("s_waitcnt vmcnt(0)" ::: "memory");
  __builtin_amdgcn_sched_barrier(0);
}
__device__ __forceinline__ bf16x8 mk8(u64 a, u64 b){
  bf16x8 r;
  __builtin_memcpy(&r, &a, 8);
  __builtin_memcpy(((char*)&r) + 8, &b, 8);
  return r;
}
__device__ __forceinline__ bf16x8 mk8w(unsigned int a0, unsigned int a1,
                                       unsigned int a2, unsigned int a3){
  unsigned int w[4] = {a0, a1, a2, a3};
  bf16x8 r; __builtin_memcpy(&r, w, 16); return r;
}

// ---------------- workspace layout (bytes) ----------------
#define OFF_HB32   0ull          // 2 dir * 2 slot * 64*512 f32      = 524288
#define OFF_HPUB   524288ull     // 2 dir * 64*512 bf16              = 131072
#define OFF_RHP    655360ull     // 2 dir * 64*512 u32 (hi|lo<<16)   = 262144
#define OFF_FLAGS  917504ull     // flag words                      = 16384
#define CTRL_BYTES 933888ull
#define OFF_XPZR   2097152ull    // 4 * SBH bf16 (d x {z,r})         = 134217728
#define OFF_XPH    136314880ull  // 2 * SBH f32  (d)                 = 134217728
#define OFF_H0     270532608ull  // 2 * SBH bf16                     = 67108864
#define OFF_WBF    337641472ull  // 6 * 4 * 512*512 bf16             = 12582912
#define WS_TOTAL   350224384ull

__global__ void sentinel_kernel(float* out){ out[0] = 12345.0f; }

// ---------------- fp32 -> bf16 weight conversion ----------------
__global__ __launch_bounds__(256) void convert_kernel(
    const float* __restrict__ Wxz, const float* __restrict__ Wxr, const float* __restrict__ Wxh,
    const float* __restrict__ Whz, const float* __restrict__ Whr, const float* __restrict__ Whh,
    unsigned short* __restrict__ wbf)
{
  const int tn = blockIdx.y;
  const float* src = (tn==0)?Wxz:(tn==1)?Wxr:(tn==2)?Wxh:(tn==3)?Whz:(tn==4)?Whr:Whh;
  const size_t base = (size_t)tn * 1048576ull;
  const size_t i = ((size_t)blockIdx.x * 256 + threadIdx.x) * 4;
  float4 v = *(const float4*)(src + i);
  ushort4 o;
  o.x = f2b(v.x); o.y = f2b(v.y); o.z = f2b(v.z); o.w = f2b(v.w);
  *(ushort4*)(wbf + base + i) = o;
}

// ---------------- x-projection GEMM (proven R1/R4 version) ----------------
__global__ __launch_bounds__(256) void xproj_kernel(
    const int layer,
    const int* __restrict__ tokens, const float* __restrict__ table,
    const unsigned short* __restrict__ h0buf, const unsigned short* __restrict__ wbf,
    const float* __restrict__ bxz, const float* __restrict__ bxr, const float* __restrict__ bxh,
    unsigned short* __restrict__ xpzr, float* __restrict__ xph)
{
  const int d = blockIdx.z / 3, gate = blockIdx.z % 3;
  const int m0 = blockIdx.x * 128, j0 = blockIdx.y * 64;
  const int tid = threadIdx.x;
  const int wv = tid >> 6, lane = tid & 63, l15 = lane & 15, l4 = lane >> 4;

  __shared__ unsigned short Ast[128][40];

  const unsigned short* wsrc = wbf + ((size_t)(gate*4 + d*2 + layer)) * 262144ull;
  const float* bias = ((gate==0) ? bxz : (gate==1) ? bxr : bxh) + (d*2 + layer)*512;
  const unsigned short* h0d = h0buf + (size_t)d * SBH;

  const int srow = tid >> 1;
  const int skc  = (tid & 1) * 16;
  const int sm   = m0 + srow;
  int stok = 0;
  if (layer == 0){
    int ss = sm >> 6, sb = sm & 63;
    stok = tokens[sb*512 + ss];
  }

  f32x4 acc[2][4];
  #pragma unroll
  for (int a = 0; a < 2; ++a)
    #pragma unroll
    for (int n = 0; n < 4; ++n) acc[a][n] = (f32x4){0.f,0.f,0.f,0.f};

  for (int k0 = 0; k0 < 512; k0 += 32){
    if (layer == 0){
      u16x8 u0 = {0,0,0,0,0,0,0,0}, u1 = {0,0,0,0,0,0,0,0};
      if (stok != 0){
        const float* src = table + (size_t)stok*512 + k0 + skc;
        float4 f0 = *(const float4*)(src);
        float4 f1 = *(const float4*)(src + 4);
        float4 f2 = *(const float4*)(src + 8);
        float4 f3 = *(const float4*)(src + 12);
        u0[0]=f2b(f0.x); u0[1]=f2b(f0.y); u0[2]=f2b(f0.z); u0[3]=f2b(f0.w);
        u0[4]=f2b(f1.x); u0[5]=f2b(f1.y); u0[6]=f2b(f1.z); u0[7]=f2b(f1.w);
        u1[0]=f2b(f2.x); u1[1]=f2b(f2.y); u1[2]=f2b(f2.z); u1[3]=f2b(f2.w);
        u1[4]=f2b(f3.x); u1[5]=f2b(f3.y); u1[6]=f2b(f3.z); u1[7]=f2b(f3.w);
      }
      *(u16x8*)&Ast[srow][skc]     = u0;
      *(u16x8*)&Ast[srow][skc + 8] = u1;
    } else {
      const unsigned short* src = h0d + (size_t)sm*512 + k0 + skc;
      *(u16x8*)&Ast[srow][skc]     = *(const u16x8*)(src);
      *(u16x8*)&Ast[srow][skc + 8] = *(const u16x8*)(src + 8);
    }
    __syncthreads();

    bf16x8 wfr[4];
    #pragma unroll
    for (int nb = 0; nb < 4; ++nb)
      wfr[nb] = *(const bf16x8*)(wsrc + (size_t)(j0 + nb*16 + l15)*512 + k0 + l4*8);
    #pragma unroll
    for (int mb = 0; mb < 2; ++mb){
      bf16x8 af = *(const bf16x8*)&Ast[(wv*2 + mb)*16 + l15][l4*8];
      #pragma unroll
      for (int nb = 0; nb < 4; ++nb)
        acc[mb][nb] = __builtin_amdgcn_mfma_f32_16x16x32_bf16(af, wfr[nb], acc[mb][nb], 0,0,0);
    }
    __syncthreads();
  }

  if (gate < 2){
    unsigned short* dst = xpzr + (size_t)(d*2 + gate) * SBH;
    #pragma unroll
    for (int mb = 0; mb < 2; ++mb)
      #pragma unroll
      for (int nb = 0; nb < 4; ++nb){
        const int col = j0 + nb*16 + l15;
        const float bv = bias[col];
        #pragma unroll
        for (int i = 0; i < 4; ++i){
          const int mrow = m0 + (wv*2 + mb)*16 + l4*4 + i;
          dst[(size_t)mrow*512 + col] = f2b(acc[mb][nb][i] + bv);
        }
      }
  } else {
    float* dst = xph + (size_t)d * SBH;
    #pragma unroll
    for (int mb = 0; mb < 2; ++mb)
      #pragma unroll
      for (int nb = 0; nb < 4; ++nb){
        const int col = j0 + nb*16 + l15;
        const float bv = bias[col];
        #pragma unroll
        for (int i = 0; i < 4; ++i){
          const int mrow = m0 + (wv*2 + mb)*16 + l4*4 + i;
          dst[(size_t)mrow*512 + col] = acc[mb][nb][i] + bv;
        }
      }
  }
}

// ---------------- persistent recurrence ----------------
// 32 WGs = 2 dir x 16 col-groups, 512 threads (8 waves), 32 cols/WG.
__global__ __launch_bounds__(512,1) void recur_kernel(
    const int layer,
    const unsigned short* __restrict__ xpzr, const float* __restrict__ xph,
    const unsigned short* __restrict__ wbf, const float* __restrict__ WhhF,
    unsigned short* __restrict__ h0buf, float* __restrict__ out,
    const int* __restrict__ lengths,
    float* __restrict__ hb32, unsigned short* __restrict__ hpub,
    unsigned int* __restrict__ rhp, int* __restrict__ flags)
{
  const int d = blockIdx.x >> 4, g = blockIdx.x & 15;
  const int tid = threadIdx.x;
  const int wv = tid >> 6, lane = tid & 63, l15 = lane & 15, l4 = lane >> 4;
  const int colg0 = g * 32;

  __shared__ float zL[64][33];
  __shared__ int lenL[64];
  __shared__ int gvL;

  if (tid < 64) lenL[tid] = lengths[tid];
  if (tid == 0) gvL = 0;

  // wave roles (identical to R7)
  const int g1  = wv >> 2;            // P1 gate: 0=z (waves 0-3), 1=r (4-7)
  const int nb1 = wv & 1;             // 16-col block within the WG's 32
  const int mh1 = (wv >> 1) & 1;      // P1 m-half (rows 0-31 / 32-63)
  const int mb2 = wv >> 1;            // P2 m-block (16 rows)
  const int jb  = colg0 + nb1*16;
  const int myj = jb + l15;

  // --- stationary weight fragments in VGPRs ---
  const unsigned short* w1 = wbf + ((size_t)((3 + g1)*4 + d*2 + layer)) * 262144ull;
  bf16x8 wf1[16];
  #pragma unroll
  for (int k0 = 0; k0 < 16; ++k0)
    wf1[k0] = *(const bf16x8*)(w1 + (size_t)(jb + l15)*512 + k0*32 + l4*8);
  const unsigned short* w2 = wbf + ((size_t)(5*4 + d*2 + layer)) * 262144ull;
  bf16x8 wf2[16];
  #pragma unroll
  for (int k0 = 0; k0 < 16; ++k0)
    wf2[k0] = *(const bf16x8*)(w2 + (size_t)(jb + l15)*512 + k0*32 + l4*8);
  bf16x8 wlo[16];
  {
    const float* wF = WhhF + ((size_t)(d*2 + layer))*262144ull + (size_t)(jb + l15)*512;
    #pragma unroll
    for (int k0 = 0; k0 < 16; ++k0){
      u16x8 lo;
      #pragma unroll
      for (int j = 0; j < 8; ++j){
        float w = wF[k0*32 + l4*8 + j];
        lo[j] = f2b(w - b2f(f2b(w)));
      }
      wlo[k0] = (bf16x8)lo;
    }
  }

  float* hb32d = hb32 + (size_t)d*2*32768;
  unsigned short* hpub_d = hpub + (size_t)d*32768;
  unsigned int*   rhp_d  = rhp  + (size_t)d*32768;
  int* rF = flags + d*256;        // 16 per-WG flag words
  int* hF = rF + 128;
  const unsigned short* xpz = xpzr + (size_t)(d*2 + 0)*SBH;
  const unsigned short* xpr = xpzr + (size_t)(d*2 + 1)*SBH;
  const float*          xpd = xph  + (size_t)d*SBH;
  const unsigned short* xp1 = (g1 == 0) ? xpz : xpr;

  int budget = 1 << 21;
  __syncthreads();

  // wave-0-only ballot poll: no barriers inside the loop, light spin
  #define WAIT_FLAGS(F, TGT)                                              \
    if (wv == 0){                                                         \
      for (;;){                                                           \
        bool ok = (lane < 16) ? (ld_sys_i32(&(F)[lane]) >= (TGT)) : true; \
        if (__all(ok)) break;                                             \
        if (--budget <= 0) break;                                         \
        __builtin_amdgcn_s_sleep(2);                                      \
      }                                                                   \
      if (lane == 0 && budget <= 0) gvL = 1;                              \
    }                                                                     \
    __syncthreads();                                                      \
    if (gvL) return;

  for (int t = 0; t < 512; ++t){
    const float* hr32 = hb32d + (t & 1)*32768;
    const int idx = (layer == 0 && d == 1) ? (511 - t) : t;
    const size_t xbase = (size_t)idx * 32768;

    // ---- wait h(t) ready (h(0) is memset) ----
    if (t > 0){ WAIT_FLAGS(hF, t) }

    // ---- hoist P1 xp scalar loads ----
    unsigned short xr1[8];
    #pragma unroll
    for (int mm = 0; mm < 2; ++mm)
      #pragma unroll
      for (int i = 0; i < 4; ++i)
        xr1[mm*4+i] = xp1[xbase + (size_t)((mh1*2+mm)*16 + l4*4 + i)*512 + myj];

    // ---- P1: direct fragment loads of h (64 u64/lane, batched) ----
    u64 hfa[64];
    #pragma unroll
    for (int mm = 0; mm < 2; ++mm)
      #pragma unroll
      for (int k0 = 0; k0 < 16; ++k0){
        const u64* p = (const u64*)(hpub_d + (size_t)((mh1*2+mm)*16 + l15)*512 + k0*32 + l4*8);
        hfa[(mm*16 + k0)*2 + 0] = ld_sys_u64(p);
        hfa[(mm*16 + k0)*2 + 1] = ld_sys_u64(p + 1);
      }

    // ---- P1 MFMA: preact = h @ Wh{z|r}^T (2 m-blocks per wave) ----
    f32x4 acc[2];
    acc[0] = (f32x4){0.f,0.f,0.f,0.f};
    acc[1] = (f32x4){0.f,0.f,0.f,0.f};
    #pragma unroll
    for (int k0 = 0; k0 < 16; ++k0){
      #pragma unroll
      for (int mm = 0; mm < 2; ++mm){
        bf16x8 a = mk8(hfa[(mm*16 + k0)*2], hfa[(mm*16 + k0)*2 + 1]);
        acc[mm] = __builtin_amdgcn_mfma_f32_16x16x32_bf16(a, wf1[k0], acc[mm], 0,0,0);
      }
    }
    if (g1 == 0){  // z
      #pragma unroll
      for (int mm = 0; mm < 2; ++mm)
        #pragma unroll
        for (int i = 0; i < 4; ++i){
          int b = (mh1*2+mm)*16 + l4*4 + i;
          float pre = acc[mm][i] + b2f(xr1[mm*4+i]);
          zL[b][nb1*16 + l15] = 1.f/(1.f + __expf(-pre));
        }
    } else {       // r -> publish rh packed hi|lo
      #pragma unroll
      for (int mm = 0; mm < 2; ++mm)
        #pragma unroll
        for (int i = 0; i < 4; ++i){
          int b = (mh1*2+mm)*16 + l4*4 + i;
          float pre = acc[mm][i] + b2f(xr1[mm*4+i]);
          float r = 1.f/(1.f + __expf(-pre));
          float rhv = r * hr32[b*512 + myj];
          unsigned short hi = f2b(rhv);
          unsigned short lo = f2b(rhv - b2f(hi));
          st_sys_u32(rhp_d + (size_t)b*512 + myj, (unsigned int)hi | ((unsigned int)lo << 16));
        }
    }
    vm0();
    __syncthreads();
    if (tid == 0) st_sys_i32(&rF[g], t + 1);

    // ---- wait all rh(t) ----
    WAIT_FLAGS(rF, t + 1)

    // ---- hoist P2 xph loads ----
    float xh[4];
    #pragma unroll
    for (int i = 0; i < 4; ++i)
      xh[i] = xpd[xbase + (size_t)(mb2*16 + l4*4 + i)*512 + myj];

    // ---- P2: direct fragment loads of rh (64 u64/lane, batched) ----
    u64 rf[64];
    #pragma unroll
    for (int k0 = 0; k0 < 16; ++k0){
      const u64* p = (const u64*)(rhp_d + (size_t)(mb2*16 + l15)*512 + k0*32 + l4*8);
      rf[k0*4 + 0] = ld_sys_u64(p);
      rf[k0*4 + 1] = ld_sys_u64(p + 1);
      rf[k0*4 + 2] = ld_sys_u64(p + 2);
      rf[k0*4 + 3] = ld_sys_u64(p + 3);
    }

    // ---- P2 MFMA: h~ = tanh(xph + rh @ Whh^T), 3-term split ----
    f32x4 acc2 = (f32x4){0.f,0.f,0.f,0.f};
    #pragma unroll
    for (int k0 = 0; k0 < 16; ++k0){
      unsigned int c[8];
      #pragma unroll
      for (int j = 0; j < 4; ++j){
        c[2*j+0] = (unsigned int)rf[k0*4 + j];
        c[2*j+1] = (unsigned int)(rf[k0*4 + j] >> 32);
      }
      unsigned int hi32[4], lo32[4];
      #pragma unroll
      for (int q = 0; q < 4; ++q){
        hi32[q] = (c[2*q] & 0xffffu) | (c[2*q+1] << 16);
        lo32[q] = (c[2*q] >> 16) | (c[2*q+1] & 0xffff0000u);
      }
      bf16x8 ahi = mk8w(hi32[0], hi32[1], hi32[2], hi32[3]);
      bf16x8 alo = mk8w(lo32[0], lo32[1], lo32[2], lo32[3]);
      acc2 = __builtin_amdgcn_mfma_f32_16x16x32_bf16(ahi, wf2[k0], acc2, 0,0,0);
      acc2 = __builtin_amdgcn_mfma_f32_16x16x32_bf16(alo, wf2[k0], acc2, 0,0,0);
      acc2 = __builtin_amdgcn_mfma_f32_16x16x32_bf16(ahi, wlo[k0], acc2, 0,0,0);
    }
    float* hw32 = hb32d + ((t + 1) & 1)*32768;
    #pragma unroll
    for (int i = 0; i < 4; ++i){
      int b = mb2*16 + l4*4 + i;
      float pre = acc2[i] + xh[i];
      float e  = __expf(-2.f*fabsf(pre));
      float th = (1.f - e)/(1.f + e);
      th = (pre < 0.f) ? -th : th;
      float z    = zL[b][nb1*16 + l15];
      float hold = hr32[b*512 + myj];
      bool  msk  = (t < lenL[b]);
      float hn   = msk ? (hold + z*(th - hold)) : hold;
      hw32[b*512 + myj] = hn;
      if (layer == 0){
        h0buf[(size_t)d*SBH + ((size_t)t*64 + b)*512 + myj] = f2b(hn);
      } else {
        int sout = d ? (511 - t) : t;
        out[((size_t)b*512 + sout)*1024 + (size_t)d*512 + myj] = msk ? hn : 0.f;
      }
    }
    __syncthreads();   // hw32 visible within WG (same CU / L1)

    // ---- publish h(t+1): each thread one u64 (4 cols) of own 32 ----
    {
      int b = tid >> 3, c4 = (tid & 7)*4;
      const float* src = hw32 + b*512 + colg0 + c4;
      unsigned short pk[4];
      #pragma unroll
      for (int j = 0; j < 4; ++j) pk[j] = f2b(src[j]);
      u64 w;
      __builtin_memcpy(&w, pk, 8);
      st_sys_u64((u64*)(hpub_d + (size_t)b*512 + colg0 + c4), w);
    }
    vm0();
    __syncthreads();
    if (tid == 0) st_sys_i32(&hF[g], t + 1);
  }
  #undef WAIT_FLAGS
}

// ---------------- host launcher ----------------
extern "C" void kernel_launch(void* const* d_in, const int* in_sizes, int n_in,
                              void* d_out, int out_size, void* d_ws, size_t ws_size,
                              hipStream_t stream)
{
  const int*   tokens  = (const int*)  d_in[0];
  const int*   lengths = (const int*)  d_in[1];
  const float* table   = (const float*)d_in[2];
  const float* Wxz = (const float*)d_in[3];
  const float* bxz = (const float*)d_in[4];
  const float* Whz = (const float*)d_in[5];
  const float* Wxr = (const float*)d_in[6];
  const float* bxr = (const float*)d_in[7];
  const float* Whr = (const float*)d_in[8];
  const float* Wxh = (const float*)d_in[9];
  const float* bxh = (const float*)d_in[10];
  const float* Whh = (const float*)d_in[11];
  float* out = (float*)d_out;

  char* ws = (char*)d_ws;
  if (ws_size < WS_TOTAL){
    sentinel_kernel<<<1, 1, 0, stream>>>(out);
    return;
  }
  float*          hb32 = (float*)         (ws + OFF_HB32);
  unsigned short* hpub = (unsigned short*)(ws + OFF_HPUB);
  unsigned int*   rhp  = (unsigned int*)  (ws + OFF_RHP);
  int*            flags= (int*)           (ws + OFF_FLAGS);
  unsigned short* xpzr = (unsigned short*)(ws + OFF_XPZR);
  float*          xph  = (float*)         (ws + OFF_XPH);
  unsigned short* h0   = (unsigned short*)(ws + OFF_H0);
  unsigned short* wbf  = (unsigned short*)(ws + OFF_WBF);

  hipMemsetAsync(ws, 0, CTRL_BYTES, stream);
  convert_kernel<<<dim3(1024, 6), 256, 0, stream>>>(Wxz, Wxr, Wxh, Whz, Whr, Whh, wbf);

  // layer 0
  xproj_kernel<<<dim3(256, 8, 6), 256, 0, stream>>>(0, tokens, table, h0, wbf,
                                                    bxz, bxr, bxh, xpzr, xph);
  recur_kernel<<<dim3(32), 512, 0, stream>>>(0, xpzr, xph, wbf, Whh, h0, out,
                                             lengths, hb32, hpub, rhp, flags);
  // layer 1
  hipMemsetAsync(ws, 0, CTRL_BYTES, stream);
  xproj_kernel<<<dim3(256, 8, 6), 256, 0, stream>>>(1, tokens, table, h0, wbf,
                                                    bxz, bxr, bxh, xpzr, xph);
  recur_kernel<<<dim3(32), 512, 0, stream>>>(1, xpzr, xph, wbf, Whh, h0, out,
                                             lengths, hb32, hpub, rhp, flags);
}

// Round 9
// 46382.703 us; speedup vs baseline: 1.1296x; 1.1296x over previous
//
#include <hip/hip_runtime.h>
#include <hip/hip_bf16.h>

// ---------------------------------------------------------------------------
// Bidirectional 2-layer GRU encoder, B=64, S=512, D=H=512.
// R9 = proven pieces only, register-residency restored:
//   - 256-thread WGs (4 waves, 1 wave/SIMD -> 512 VGPR budget): wf1/wf2/wlo
//     (192 VGPRs) truly stationary (R7/R8 silently spilled at 512 threads).
//   - R6 wave roles + XOR-swizzled LDS staging; R7 per-WG flags; R8 wave0
//     ballot poll.
//   - single-batch staging (h: 32 u64/thr, rh: 64 u64/thr) -> 2 RTT/step.
//   - h fp32 state in LDS (own cols); xp prefetched before the poll.
// Math identical to R4..R8 (absmax 2.441e-4).
// ---------------------------------------------------------------------------

typedef short bf16x8 __attribute__((ext_vector_type(8)));
typedef float f32x4  __attribute__((ext_vector_type(4)));
typedef unsigned short u16x8 __attribute__((ext_vector_type(8)));
typedef unsigned long long u64;

#define SBH 16777216ull   // S*B*H = 512*64*512
#define NWG_DIR 16

__device__ __forceinline__ unsigned short f2b(float f){
  __hip_bfloat16 h = __float2bfloat16(f);
  unsigned short u; __builtin_memcpy(&u, &h, 2); return u;
}
__device__ __forceinline__ float b2f(unsigned short u){
  __hip_bfloat16 h; __builtin_memcpy(&h, &u, 2); return __bfloat162float(h);
}

__device__ __forceinline__ u64 ld_sys_u64(const u64* p){
  return __hip_atomic_load(p, __ATOMIC_RELAXED, __HIP_MEMORY_SCOPE_SYSTEM);
}
__device__ __forceinline__ void st_sys_u64(u64* p, u64 v){
  __hip_atomic_store(p, v, __ATOMIC_RELAXED, __HIP_MEMORY_SCOPE_SYSTEM);
}
__device__ __forceinline__ void st_sys_u32(unsigned int* p, unsigned int v){
  __hip_atomic_store(p, v, __ATOMIC_RELAXED, __HIP_MEMORY_SCOPE_SYSTEM);
}
__device__ __forceinline__ int ld_sys_i32(const int* p){
  return __hip_atomic_load(p, __ATOMIC_RELAXED, __HIP_MEMORY_SCOPE_SYSTEM);
}
__device__ __forceinline__ void st_sys_i32(int* p, int v){
  __hip_atomic_store(p, v, __ATOMIC_RELAXED, __HIP_MEMORY_SCOPE_SYSTEM);
}
__device__ __forceinline__ void vm0(){
  asm volatile("s_waitcnt vmcnt(0)" ::: "memory");
  __builtin_amdgcn_sched_barrier(0);
}
// LDS swizzle: spread 1024B-stride rows across banks; bijective within row.
__device__ __forceinline__ int swz(int byte){
  return byte ^ (((byte >> 10) & 7) << 4);
}

// ---------------- workspace layout (bytes) ----------------
#define OFF_HPUB   0ull          // 2 dir * 64*512 bf16              = 131072
#define OFF_RHP    131072ull     // 2 dir * 64*512 u32 (hi|lo<<16)   = 262144
#define OFF_FLAGS  393216ull     // 2 dir * 256 int                  = 2048
#define CTRL_BYTES 395264ull
#define OFF_XPZR   2097152ull    // 4 * SBH bf16 (d x {z,r})         = 134217728
#define OFF_XPH    136314880ull  // 2 * SBH f32  (d)                 = 134217728
#define OFF_H0     270532608ull  // 2 * SBH bf16                     = 67108864
#define OFF_WBF    337641472ull  // 6 * 4 * 512*512 bf16             = 12582912
#define WS_TOTAL   350224384ull

__global__ void sentinel_kernel(float* out){ out[0] = 12345.0f; }

// ---------------- fp32 -> bf16 weight conversion ----------------
__global__ __launch_bounds__(256) void convert_kernel(
    const float* __restrict__ Wxz, const float* __restrict__ Wxr, const float* __restrict__ Wxh,
    const float* __restrict__ Whz, const float* __restrict__ Whr, const float* __restrict__ Whh,
    unsigned short* __restrict__ wbf)
{
  const int tn = blockIdx.y;
  const float* src = (tn==0)?Wxz:(tn==1)?Wxr:(tn==2)?Wxh:(tn==3)?Whz:(tn==4)?Whr:Whh;
  const size_t base = (size_t)tn * 1048576ull;
  const size_t i = ((size_t)blockIdx.x * 256 + threadIdx.x) * 4;
  float4 v = *(const float4*)(src + i);
  ushort4 o;
  o.x = f2b(v.x); o.y = f2b(v.y); o.z = f2b(v.z); o.w = f2b(v.w);
  *(ushort4*)(wbf + base + i) = o;
}

// ---------------- x-projection GEMM (proven R1/R4 version) ----------------
__global__ __launch_bounds__(256) void xproj_kernel(
    const int layer,
    const int* __restrict__ tokens, const float* __restrict__ table,
    const unsigned short* __restrict__ h0buf, const unsigned short* __restrict__ wbf,
    const float* __restrict__ bxz, const float* __restrict__ bxr, const float* __restrict__ bxh,
    unsigned short* __restrict__ xpzr, float* __restrict__ xph)
{
  const int d = blockIdx.z / 3, gate = blockIdx.z % 3;
  const int m0 = blockIdx.x * 128, j0 = blockIdx.y * 64;
  const int tid = threadIdx.x;
  const int wv = tid >> 6, lane = tid & 63, l15 = lane & 15, l4 = lane >> 4;

  __shared__ unsigned short Ast[128][40];

  const unsigned short* wsrc = wbf + ((size_t)(gate*4 + d*2 + layer)) * 262144ull;
  const float* bias = ((gate==0) ? bxz : (gate==1) ? bxr : bxh) + (d*2 + layer)*512;
  const unsigned short* h0d = h0buf + (size_t)d * SBH;

  const int srow = tid >> 1;
  const int skc  = (tid & 1) * 16;
  const int sm   = m0 + srow;
  int stok = 0;
  if (layer == 0){
    int ss = sm >> 6, sb = sm & 63;
    stok = tokens[sb*512 + ss];
  }

  f32x4 acc[2][4];
  #pragma unroll
  for (int a = 0; a < 2; ++a)
    #pragma unroll
    for (int n = 0; n < 4; ++n) acc[a][n] = (f32x4){0.f,0.f,0.f,0.f};

  for (int k0 = 0; k0 < 512; k0 += 32){
    if (layer == 0){
      u16x8 u0 = {0,0,0,0,0,0,0,0}, u1 = {0,0,0,0,0,0,0,0};
      if (stok != 0){
        const float* src = table + (size_t)stok*512 + k0 + skc;
        float4 f0 = *(const float4*)(src);
        float4 f1 = *(const float4*)(src + 4);
        float4 f2 = *(const float4*)(src + 8);
        float4 f3 = *(const float4*)(src + 12);
        u0[0]=f2b(f0.x); u0[1]=f2b(f0.y); u0[2]=f2b(f0.z); u0[3]=f2b(f0.w);
        u0[4]=f2b(f1.x); u0[5]=f2b(f1.y); u0[6]=f2b(f1.z); u0[7]=f2b(f1.w);
        u1[0]=f2b(f2.x); u1[1]=f2b(f2.y); u1[2]=f2b(f2.z); u1[3]=f2b(f2.w);
        u1[4]=f2b(f3.x); u1[5]=f2b(f3.y); u1[6]=f2b(f3.z); u1[7]=f2b(f3.w);
      }
      *(u16x8*)&Ast[srow][skc]     = u0;
      *(u16x8*)&Ast[srow][skc + 8] = u1;
    } else {
      const unsigned short* src = h0d + (size_t)sm*512 + k0 + skc;
      *(u16x8*)&Ast[srow][skc]     = *(const u16x8*)(src);
      *(u16x8*)&Ast[srow][skc + 8] = *(const u16x8*)(src + 8);
    }
    __syncthreads();

    bf16x8 wfr[4];
    #pragma unroll
    for (int nb = 0; nb < 4; ++nb)
      wfr[nb] = *(const bf16x8*)(wsrc + (size_t)(j0 + nb*16 + l15)*512 + k0 + l4*8);
    #pragma unroll
    for (int mb = 0; mb < 2; ++mb){
      bf16x8 af = *(const bf16x8*)&Ast[(wv*2 + mb)*16 + l15][l4*8];
      #pragma unroll
      for (int nb = 0; nb < 4; ++nb)
        acc[mb][nb] = __builtin_amdgcn_mfma_f32_16x16x32_bf16(af, wfr[nb], acc[mb][nb], 0,0,0);
    }
    __syncthreads();
  }

  if (gate < 2){
    unsigned short* dst = xpzr + (size_t)(d*2 + gate) * SBH;
    #pragma unroll
    for (int mb = 0; mb < 2; ++mb)
      #pragma unroll
      for (int nb = 0; nb < 4; ++nb){
        const int col = j0 + nb*16 + l15;
        const float bv = bias[col];
        #pragma unroll
        for (int i = 0; i < 4; ++i){
          const int mrow = m0 + (wv*2 + mb)*16 + l4*4 + i;
          dst[(size_t)mrow*512 + col] = f2b(acc[mb][nb][i] + bv);
        }
      }
  } else {
    float* dst = xph + (size_t)d * SBH;
    #pragma unroll
    for (int mb = 0; mb < 2; ++mb)
      #pragma unroll
      for (int nb = 0; nb < 4; ++nb){
        const int col = j0 + nb*16 + l15;
        const float bv = bias[col];
        #pragma unroll
        for (int i = 0; i < 4; ++i){
          const int mrow = m0 + (wv*2 + mb)*16 + l4*4 + i;
          dst[(size_t)mrow*512 + col] = acc[mb][nb][i] + bv;
        }
      }
  }
}

// ---------------- persistent recurrence ----------------
// 32 WGs = 2 dir x 16 col-groups, 256 threads (4 waves), 32 cols/WG.
__global__ __launch_bounds__(256,1) void recur_kernel(
    const int layer,
    const unsigned short* __restrict__ xpzr, const float* __restrict__ xph,
    const unsigned short* __restrict__ wbf, const float* __restrict__ WhhF,
    unsigned short* __restrict__ h0buf, float* __restrict__ out,
    const int* __restrict__ lengths,
    unsigned short* __restrict__ hpub, unsigned int* __restrict__ rhp,
    int* __restrict__ flags)
{
  const int d = blockIdx.x >> 4, g = blockIdx.x & 15;
  const int tid = threadIdx.x;
  const int wv = tid >> 6, lane = tid & 63, l15 = lane & 15, l4 = lane >> 4;
  const int colg0 = g * 32;

  __shared__ unsigned short hst[64*512];   // P1: h(t); P2: rh-hi (swizzled)
  __shared__ unsigned short rhL[64*512];   // rh-lo (swizzled)
  __shared__ float zL[64][33];
  __shared__ float h32[64][33];            // own 32 cols, fp32 state
  __shared__ int lenL[64];
  __shared__ int gvL;

  if (tid < 64) lenL[tid] = lengths[tid];
  if (tid == 0) gvL = 0;
  #pragma unroll
  for (int q = 0; q < 9; ++q){
    int e = q*256 + tid;
    if (e < 64*33) ((float*)h32)[e] = 0.f;
  }

  // wave roles (R6): waves 0-1 = z, waves 2-3 = r; col-half = wv&1
  const int p1g = wv >> 1;
  const int cb  = wv & 1;
  const int jb  = colg0 + cb*16;
  const int myj = jb + l15;
  const int jcl = cb*16 + l15;             // column within own 32

  // --- stationary weight fragments in VGPRs (192 VGPRs) ---
  const unsigned short* w1 = wbf + ((size_t)((3 + p1g)*4 + d*2 + layer)) * 262144ull;
  bf16x8 wf1[16];
  #pragma unroll
  for (int k0 = 0; k0 < 16; ++k0)
    wf1[k0] = *(const bf16x8*)(w1 + (size_t)(jb + l15)*512 + k0*32 + l4*8);
  const unsigned short* w2 = wbf + ((size_t)(5*4 + d*2 + layer)) * 262144ull;
  bf16x8 wf2[16];
  #pragma unroll
  for (int k0 = 0; k0 < 16; ++k0)
    wf2[k0] = *(const bf16x8*)(w2 + (size_t)(jb + l15)*512 + k0*32 + l4*8);
  bf16x8 wlo[16];
  {
    const float* wF = WhhF + ((size_t)(d*2 + layer))*262144ull + (size_t)(jb + l15)*512;
    #pragma unroll
    for (int k0 = 0; k0 < 16; ++k0){
      u16x8 lo;
      #pragma unroll
      for (int j = 0; j < 8; ++j){
        float w = wF[k0*32 + l4*8 + j];
        lo[j] = f2b(w - b2f(f2b(w)));
      }
      wlo[k0] = (bf16x8)lo;
    }
  }

  unsigned short* hpub_d = hpub + (size_t)d*32768;
  unsigned int*   rhp_d  = rhp  + (size_t)d*32768;
  int* rF = flags + d*256;
  int* hF = rF + 128;
  const unsigned short* xpz = xpzr + (size_t)(d*2 + 0)*SBH;
  const unsigned short* xpr = xpzr + (size_t)(d*2 + 1)*SBH;
  const float*          xpd = xph  + (size_t)d*SBH;
  const unsigned short* xp1 = (p1g == 0) ? xpz : xpr;

  int budget = 1 << 21;
  __syncthreads();

  // wave-0-only ballot poll; others park at the barrier.
  #define WAIT_FLAGS(F, TGT)                                              \
    if (wv == 0){                                                         \
      for (;;){                                                           \
        bool ok = (lane < 16) ? (ld_sys_i32(&(F)[lane]) >= (TGT)) : true; \
        if (__all(ok)) break;                                             \
        if (--budget <= 0) break;                                         \
        __builtin_amdgcn_s_sleep(1);                                      \
      }                                                                   \
      if (lane == 0 && budget <= 0) gvL = 1;                              \
    }                                                                     \
    __syncthreads();                                                      \
    if (gvL) return;

  for (int t = 0; t < 512; ++t){
    const int idx = (layer == 0 && d == 1) ? (511 - t) : t;
    const size_t xbase = (size_t)idx * 32768;

    // ---- prefetch this step's xp (latency hides under the poll) ----
    unsigned short xr1[16];
    #pragma unroll
    for (int m = 0; m < 4; ++m)
      #pragma unroll
      for (int i = 0; i < 4; ++i)
        xr1[m*4+i] = xp1[xbase + (size_t)(m*16 + l4*4 + i)*512 + myj];
    float xh[8];
    #pragma unroll
    for (int m = 0; m < 2; ++m)
      #pragma unroll
      for (int i = 0; i < 4; ++i)
        xh[m*4+i] = xpd[xbase + (size_t)(((wv>>1)*2+m)*16 + l4*4 + i)*512 + myj];

    // ---- wait h(t) ready (h(0) is memset) ----
    if (t > 0){ WAIT_FLAGS(hF, t) }

    // ---- stage h(t) -> hst: ONE batch of 32 u64/thread, swizzled ----
    {
      const u64* src = (const u64*)hpub_d;   // 8192 u64 = [64][512] bf16
      u64 v[32];
      #pragma unroll
      for (int j = 0; j < 32; ++j)
        v[j] = ld_sys_u64(src + j*256 + tid);
      vm0();
      #pragma unroll
      for (int j = 0; j < 32; ++j){
        int byte = (j*256 + tid) * 8;
        *(u64*)((char*)hst + swz(byte)) = v[j];
      }
    }
    __syncthreads();

    // ---- P1: preact = h @ Wh{z|r}^T, 4 m-blocks per wave ----
    f32x4 acc[4];
    #pragma unroll
    for (int m = 0; m < 4; ++m) acc[m] = (f32x4){0.f,0.f,0.f,0.f};
    #pragma unroll
    for (int k0 = 0; k0 < 16; ++k0){
      #pragma unroll
      for (int m = 0; m < 4; ++m){
        int byte = (m*16 + l15)*1024 + k0*64 + l4*16;
        bf16x8 a = *(const bf16x8*)((const char*)hst + swz(byte));
        acc[m] = __builtin_amdgcn_mfma_f32_16x16x32_bf16(a, wf1[k0], acc[m], 0,0,0);
      }
    }
    if (p1g == 0){  // z waves
      #pragma unroll
      for (int m = 0; m < 4; ++m)
        #pragma unroll
        for (int i = 0; i < 4; ++i){
          int b = m*16 + l4*4 + i;
          float pre = acc[m][i] + b2f(xr1[m*4+i]);
          zL[b][jcl] = 1.f/(1.f + __expf(-pre));
        }
    } else {        // r waves: rh = r*h, publish packed hi|lo
      #pragma unroll
      for (int m = 0; m < 4; ++m)
        #pragma unroll
        for (int i = 0; i < 4; ++i){
          int b = m*16 + l4*4 + i;
          float pre = acc[m][i] + b2f(xr1[m*4+i]);
          float r = 1.f/(1.f + __expf(-pre));
          float rhv = r * h32[b][jcl];
          unsigned short hi = f2b(rhv);
          unsigned short lo = f2b(rhv - b2f(hi));
          st_sys_u32(rhp_d + (size_t)b*512 + myj, (unsigned int)hi | ((unsigned int)lo << 16));
        }
    }
    vm0();
    __syncthreads();
    if (tid == 0) st_sys_i32(&rF[g], t + 1);

    // ---- wait all rh(t) ----
    WAIT_FLAGS(rF, t + 1)

    // ---- stage rh -> hst(hi) + rhL(lo): ONE batch of 64 u64/thread ----
    {
      const u64* rsrc = (const u64*)rhp_d;   // 16384 u64 = [64][512] u32
      u64 v[64];
      #pragma unroll
      for (int j = 0; j < 64; ++j)
        v[j] = ld_sys_u64(rsrc + j*256 + tid);
      vm0();
      #pragma unroll
      for (int j = 0; j < 64; ++j){
        int gu = j*256 + tid;                 // element-pair index
        unsigned int x0 = (unsigned int)v[j], x1 = (unsigned int)(v[j] >> 32);
        unsigned int hi = (x0 & 0xffffu) | (x1 << 16);
        unsigned int lo = (x0 >> 16) | (x1 & 0xffff0000u);
        int byte = (gu >> 8)*1024 + (gu & 255)*4;
        int ba = swz(byte);
        *(unsigned int*)((char*)hst + ba) = hi;
        *(unsigned int*)((char*)rhL + ba) = lo;
      }
    }
    __syncthreads();

    // ---- P2: h~ = tanh(xph + rh @ Whh^T), 3-term split, 2 m-blocks ----
    f32x4 acc2[2];
    acc2[0] = (f32x4){0.f,0.f,0.f,0.f};
    acc2[1] = (f32x4){0.f,0.f,0.f,0.f};
    #pragma unroll
    for (int k0 = 0; k0 < 16; ++k0){
      #pragma unroll
      for (int m = 0; m < 2; ++m){
        int mb = (wv >> 1)*2 + m;
        int byte = (mb*16 + l15)*1024 + k0*64 + l4*16;
        int ba = swz(byte);
        bf16x8 ahi = *(const bf16x8*)((const char*)hst + ba);
        bf16x8 alo = *(const bf16x8*)((const char*)rhL + ba);
        acc2[m] = __builtin_amdgcn_mfma_f32_16x16x32_bf16(ahi, wf2[k0], acc2[m], 0,0,0);
        acc2[m] = __builtin_amdgcn_mfma_f32_16x16x32_bf16(alo, wf2[k0], acc2[m], 0,0,0);
        acc2[m] = __builtin_amdgcn_mfma_f32_16x16x32_bf16(ahi, wlo[k0], acc2[m], 0,0,0);
      }
    }
    #pragma unroll
    for (int m = 0; m < 2; ++m){
      #pragma unroll
      for (int i = 0; i < 4; ++i){
        int b = ((wv >> 1)*2 + m)*16 + l4*4 + i;
        float pre = acc2[m][i] + xh[m*4+i];
        float e  = __expf(-2.f*fabsf(pre));
        float th = (1.f - e)/(1.f + e);
        th = (pre < 0.f) ? -th : th;
        float z    = zL[b][jcl];
        float hold = h32[b][jcl];
        bool  msk  = (t < lenL[b]);
        float hn   = msk ? (hold + z*(th - hold)) : hold;
        h32[b][jcl] = hn;
        if (layer == 0){
          h0buf[(size_t)d*SBH + ((size_t)t*64 + b)*512 + myj] = f2b(hn);
        } else {
          int sout = d ? (511 - t) : t;
          out[((size_t)b*512 + sout)*1024 + (size_t)d*512 + myj] = msk ? hn : 0.f;
        }
      }
    }
    __syncthreads();   // h32 complete before publish reads

    // ---- publish h(t+1): each thread packs 8 cols (2 u64) of own 32 ----
    {
      int b = tid >> 2, c8 = (tid & 3)*8;
      unsigned short pk[8];
      #pragma unroll
      for (int j = 0; j < 8; ++j) pk[j] = f2b(h32[b][c8 + j]);
      u64 w0, w1;
      __builtin_memcpy(&w0, pk, 8);
      __builtin_memcpy(&w1, pk + 4, 8);
      u64* dst = (u64*)(hpub_d + (size_t)b*512 + colg0 + c8);
      st_sys_u64(dst + 0, w0);
      st_sys_u64(dst + 1, w1);
    }
    vm0();
    __syncthreads();
    if (tid == 0) st_sys_i32(&hF[g], t + 1);
  }
  #undef WAIT_FLAGS
}

// ---------------- host launcher ----------------
extern "C" void kernel_launch(void* const* d_in, const int* in_sizes, int n_in,
                              void* d_out, int out_size, void* d_ws, size_t ws_size,
                              hipStream_t stream)
{
  const int*   tokens  = (const int*)  d_in[0];
  const int*   lengths = (const int*)  d_in[1];
  const float* table   = (const float*)d_in[2];
  const float* Wxz = (const float*)d_in[3];
  const float* bxz = (const float*)d_in[4];
  const float* Whz = (const float*)d_in[5];
  const float* Wxr = (const float*)d_in[6];
  const float* bxr = (const float*)d_in[7];
  const float* Whr = (const float*)d_in[8];
  const float* Wxh = (const float*)d_in[9];
  const float* bxh = (const float*)d_in[10];
  const float* Whh = (const float*)d_in[11];
  float* out = (float*)d_out;

  char* ws = (char*)d_ws;
  if (ws_size < WS_TOTAL){
    sentinel_kernel<<<1, 1, 0, stream>>>(out);
    return;
  }
  unsigned short* hpub = (unsigned short*)(ws + OFF_HPUB);
  unsigned int*   rhp  = (unsigned int*)  (ws + OFF_RHP);
  int*            flags= (int*)           (ws + OFF_FLAGS);
  unsigned short* xpzr = (unsigned short*)(ws + OFF_XPZR);
  float*          xph  = (float*)         (ws + OFF_XPH);
  unsigned short* h0   = (unsigned short*)(ws + OFF_H0);
  unsigned short* wbf  = (unsigned short*)(ws + OFF_WBF);

  hipMemsetAsync(ws, 0, CTRL_BYTES, stream);
  convert_kernel<<<dim3(1024, 6), 256, 0, stream>>>(Wxz, Wxr, Wxh, Whz, Whr, Whh, wbf);

  // layer 0
  xproj_kernel<<<dim3(256, 8, 6), 256, 0, stream>>>(0, tokens, table, h0, wbf,
                                                    bxz, bxr, bxh, xpzr, xph);
  recur_kernel<<<dim3(32), 256, 0, stream>>>(0, xpzr, xph, wbf, Whh, h0, out,
                                             lengths, hpub, rhp, flags);
  // layer 1
  hipMemsetAsync(ws, 0, CTRL_BYTES, stream);
  xproj_kernel<<<dim3(256, 8, 6), 256, 0, stream>>>(1, tokens, table, h0, wbf,
                                                    bxz, bxr, bxh, xpzr, xph);
  recur_kernel<<<dim3(32), 256, 0, stream>>>(1, xpzr, xph, wbf, Whh, h0, out,
                                             lengths, hpub, rhp, flags);
}

// Round 10
// 29749.899 us; speedup vs baseline: 1.7612x; 1.5591x over previous
//
#include <hip/hip_runtime.h>
#include <hip/hip_bf16.h>

// ---------------------------------------------------------------------------
// Bidirectional 2-layer GRU encoder, B=64, S=512, D=H=512.
// R10 = R9 with the exchange moved from SYSTEM scope (HBM-serviced on gfx950,
// per R9's FETCH_SIZE evidence) to AGENT scope (device-coherent -> L3):
//   - all exchange/flag atomics agent-scope relaxed (compiler cache bits)
//   - rh staging in 2x32 batches (bounded regs), staggered per-WG read order
// Math identical to R4..R9 (absmax 2.441e-4).
// ---------------------------------------------------------------------------

typedef short bf16x8 __attribute__((ext_vector_type(8)));
typedef float f32x4  __attribute__((ext_vector_type(4)));
typedef unsigned short u16x8 __attribute__((ext_vector_type(8)));
typedef unsigned long long u64;

#define SBH 16777216ull   // S*B*H = 512*64*512
#define NWG_DIR 16

__device__ __forceinline__ unsigned short f2b(float f){
  __hip_bfloat16 h = __float2bfloat16(f);
  unsigned short u; __builtin_memcpy(&u, &h, 2); return u;
}
__device__ __forceinline__ float b2f(unsigned short u){
  __hip_bfloat16 h; __builtin_memcpy(&h, &u, 2); return __bfloat162float(h);
}

__device__ __forceinline__ u64 ld_ag_u64(const u64* p){
  return __hip_atomic_load(p, __ATOMIC_RELAXED, __HIP_MEMORY_SCOPE_AGENT);
}
__device__ __forceinline__ void st_ag_u64(u64* p, u64 v){
  __hip_atomic_store(p, v, __ATOMIC_RELAXED, __HIP_MEMORY_SCOPE_AGENT);
}
__device__ __forceinline__ void st_ag_u32(unsigned int* p, unsigned int v){
  __hip_atomic_store(p, v, __ATOMIC_RELAXED, __HIP_MEMORY_SCOPE_AGENT);
}
__device__ __forceinline__ int ld_ag_i32(const int* p){
  return __hip_atomic_load(p, __ATOMIC_RELAXED, __HIP_MEMORY_SCOPE_AGENT);
}
__device__ __forceinline__ void st_ag_i32(int* p, int v){
  __hip_atomic_store(p, v, __ATOMIC_RELAXED, __HIP_MEMORY_SCOPE_AGENT);
}
__device__ __forceinline__ void vm0(){
  asm volatile("s_waitcnt vmcnt(0)" ::: "memory");
  __builtin_amdgcn_sched_barrier(0);
}
// LDS swizzle: spread 1024B-stride rows across banks; bijective within row.
__device__ __forceinline__ int swz(int byte){
  return byte ^ (((byte >> 10) & 7) << 4);
}

// ---------------- workspace layout (bytes) ----------------
#define OFF_HPUB   0ull          // 2 dir * 64*512 bf16              = 131072
#define OFF_RHP    131072ull     // 2 dir * 64*512 u32 (hi|lo<<16)   = 262144
#define OFF_FLAGS  393216ull     // 2 dir * 256 int                  = 2048
#define CTRL_BYTES 395264ull
#define OFF_XPZR   2097152ull    // 4 * SBH bf16 (d x {z,r})         = 134217728
#define OFF_XPH    136314880ull  // 2 * SBH f32  (d)                 = 134217728
#define OFF_H0     270532608ull  // 2 * SBH bf16                     = 67108864
#define OFF_WBF    337641472ull  // 6 * 4 * 512*512 bf16             = 12582912
#define WS_TOTAL   350224384ull

__global__ void sentinel_kernel(float* out){ out[0] = 12345.0f; }

// ---------------- fp32 -> bf16 weight conversion ----------------
__global__ __launch_bounds__(256) void convert_kernel(
    const float* __restrict__ Wxz, const float* __restrict__ Wxr, const float* __restrict__ Wxh,
    const float* __restrict__ Whz, const float* __restrict__ Whr, const float* __restrict__ Whh,
    unsigned short* __restrict__ wbf)
{
  const int tn = blockIdx.y;
  const float* src = (tn==0)?Wxz:(tn==1)?Wxr:(tn==2)?Wxh:(tn==3)?Whz:(tn==4)?Whr:Whh;
  const size_t base = (size_t)tn * 1048576ull;
  const size_t i = ((size_t)blockIdx.x * 256 + threadIdx.x) * 4;
  float4 v = *(const float4*)(src + i);
  ushort4 o;
  o.x = f2b(v.x); o.y = f2b(v.y); o.z = f2b(v.z); o.w = f2b(v.w);
  *(ushort4*)(wbf + base + i) = o;
}

// ---------------- x-projection GEMM (proven R1/R4 version) ----------------
__global__ __launch_bounds__(256) void xproj_kernel(
    const int layer,
    const int* __restrict__ tokens, const float* __restrict__ table,
    const unsigned short* __restrict__ h0buf, const unsigned short* __restrict__ wbf,
    const float* __restrict__ bxz, const float* __restrict__ bxr, const float* __restrict__ bxh,
    unsigned short* __restrict__ xpzr, float* __restrict__ xph)
{
  const int d = blockIdx.z / 3, gate = blockIdx.z % 3;
  const int m0 = blockIdx.x * 128, j0 = blockIdx.y * 64;
  const int tid = threadIdx.x;
  const int wv = tid >> 6, lane = tid & 63, l15 = lane & 15, l4 = lane >> 4;

  __shared__ unsigned short Ast[128][40];

  const unsigned short* wsrc = wbf + ((size_t)(gate*4 + d*2 + layer)) * 262144ull;
  const float* bias = ((gate==0) ? bxz : (gate==1) ? bxr : bxh) + (d*2 + layer)*512;
  const unsigned short* h0d = h0buf + (size_t)d * SBH;

  const int srow = tid >> 1;
  const int skc  = (tid & 1) * 16;
  const int sm   = m0 + srow;
  int stok = 0;
  if (layer == 0){
    int ss = sm >> 6, sb = sm & 63;
    stok = tokens[sb*512 + ss];
  }

  f32x4 acc[2][4];
  #pragma unroll
  for (int a = 0; a < 2; ++a)
    #pragma unroll
    for (int n = 0; n < 4; ++n) acc[a][n] = (f32x4){0.f,0.f,0.f,0.f};

  for (int k0 = 0; k0 < 512; k0 += 32){
    if (layer == 0){
      u16x8 u0 = {0,0,0,0,0,0,0,0}, u1 = {0,0,0,0,0,0,0,0};
      if (stok != 0){
        const float* src = table + (size_t)stok*512 + k0 + skc;
        float4 f0 = *(const float4*)(src);
        float4 f1 = *(const float4*)(src + 4);
        float4 f2 = *(const float4*)(src + 8);
        float4 f3 = *(const float4*)(src + 12);
        u0[0]=f2b(f0.x); u0[1]=f2b(f0.y); u0[2]=f2b(f0.z); u0[3]=f2b(f0.w);
        u0[4]=f2b(f1.x); u0[5]=f2b(f1.y); u0[6]=f2b(f1.z); u0[7]=f2b(f1.w);
        u1[0]=f2b(f2.x); u1[1]=f2b(f2.y); u1[2]=f2b(f2.z); u1[3]=f2b(f2.w);
        u1[4]=f2b(f3.x); u1[5]=f2b(f3.y); u1[6]=f2b(f3.z); u1[7]=f2b(f3.w);
      }
      *(u16x8*)&Ast[srow][skc]     = u0;
      *(u16x8*)&Ast[srow][skc + 8] = u1;
    } else {
      const unsigned short* src = h0d + (size_t)sm*512 + k0 + skc;
      *(u16x8*)&Ast[srow][skc]     = *(const u16x8*)(src);
      *(u16x8*)&Ast[srow][skc + 8] = *(const u16x8*)(src + 8);
    }
    __syncthreads();

    bf16x8 wfr[4];
    #pragma unroll
    for (int nb = 0; nb < 4; ++nb)
      wfr[nb] = *(const bf16x8*)(wsrc + (size_t)(j0 + nb*16 + l15)*512 + k0 + l4*8);
    #pragma unroll
    for (int mb = 0; mb < 2; ++mb){
      bf16x8 af = *(const bf16x8*)&Ast[(wv*2 + mb)*16 + l15][l4*8];
      #pragma unroll
      for (int nb = 0; nb < 4; ++nb)
        acc[mb][nb] = __builtin_amdgcn_mfma_f32_16x16x32_bf16(af, wfr[nb], acc[mb][nb], 0,0,0);
    }
    __syncthreads();
  }

  if (gate < 2){
    unsigned short* dst = xpzr + (size_t)(d*2 + gate) * SBH;
    #pragma unroll
    for (int mb = 0; mb < 2; ++mb)
      #pragma unroll
      for (int nb = 0; nb < 4; ++nb){
        const int col = j0 + nb*16 + l15;
        const float bv = bias[col];
        #pragma unroll
        for (int i = 0; i < 4; ++i){
          const int mrow = m0 + (wv*2 + mb)*16 + l4*4 + i;
          dst[(size_t)mrow*512 + col] = f2b(acc[mb][nb][i] + bv);
        }
      }
  } else {
    float* dst = xph + (size_t)d * SBH;
    #pragma unroll
    for (int mb = 0; mb < 2; ++mb)
      #pragma unroll
      for (int nb = 0; nb < 4; ++nb){
        const int col = j0 + nb*16 + l15;
        const float bv = bias[col];
        #pragma unroll
        for (int i = 0; i < 4; ++i){
          const int mrow = m0 + (wv*2 + mb)*16 + l4*4 + i;
          dst[(size_t)mrow*512 + col] = acc[mb][nb][i] + bv;
        }
      }
  }
}

// ---------------- persistent recurrence ----------------
// 32 WGs = 2 dir x 16 col-groups, 256 threads (4 waves), 32 cols/WG.
__global__ __launch_bounds__(256,1) void recur_kernel(
    const int layer,
    const unsigned short* __restrict__ xpzr, const float* __restrict__ xph,
    const unsigned short* __restrict__ wbf, const float* __restrict__ WhhF,
    unsigned short* __restrict__ h0buf, float* __restrict__ out,
    const int* __restrict__ lengths,
    unsigned short* __restrict__ hpub, unsigned int* __restrict__ rhp,
    int* __restrict__ flags)
{
  const int d = blockIdx.x >> 4, g = blockIdx.x & 15;
  const int tid = threadIdx.x;
  const int wv = tid >> 6, lane = tid & 63, l15 = lane & 15, l4 = lane >> 4;
  const int colg0 = g * 32;

  __shared__ unsigned short hst[64*512];   // P1: h(t); P2: rh-hi (swizzled)
  __shared__ unsigned short rhL[64*512];   // rh-lo (swizzled)
  __shared__ float zL[64][33];
  __shared__ float h32[64][33];            // own 32 cols, fp32 state
  __shared__ int lenL[64];
  __shared__ int gvL;

  if (tid < 64) lenL[tid] = lengths[tid];
  if (tid == 0) gvL = 0;
  #pragma unroll
  for (int q = 0; q < 9; ++q){
    int e = q*256 + tid;
    if (e < 64*33) ((float*)h32)[e] = 0.f;
  }

  // wave roles (R6): waves 0-1 = z, waves 2-3 = r; col-half = wv&1
  const int p1g = wv >> 1;
  const int cb  = wv & 1;
  const int jb  = colg0 + cb*16;
  const int myj = jb + l15;
  const int jcl = cb*16 + l15;             // column within own 32

  // --- stationary weight fragments in VGPRs (192 VGPRs) ---
  const unsigned short* w1 = wbf + ((size_t)((3 + p1g)*4 + d*2 + layer)) * 262144ull;
  bf16x8 wf1[16];
  #pragma unroll
  for (int k0 = 0; k0 < 16; ++k0)
    wf1[k0] = *(const bf16x8*)(w1 + (size_t)(jb + l15)*512 + k0*32 + l4*8);
  const unsigned short* w2 = wbf + ((size_t)(5*4 + d*2 + layer)) * 262144ull;
  bf16x8 wf2[16];
  #pragma unroll
  for (int k0 = 0; k0 < 16; ++k0)
    wf2[k0] = *(const bf16x8*)(w2 + (size_t)(jb + l15)*512 + k0*32 + l4*8);
  bf16x8 wlo[16];
  {
    const float* wF = WhhF + ((size_t)(d*2 + layer))*262144ull + (size_t)(jb + l15)*512;
    #pragma unroll
    for (int k0 = 0; k0 < 16; ++k0){
      u16x8 lo;
      #pragma unroll
      for (int j = 0; j < 8; ++j){
        float w = wF[k0*32 + l4*8 + j];
        lo[j] = f2b(w - b2f(f2b(w)));
      }
      wlo[k0] = (bf16x8)lo;
    }
  }

  unsigned short* hpub_d = hpub + (size_t)d*32768;
  unsigned int*   rhp_d  = rhp  + (size_t)d*32768;
  int* rF = flags + d*256;
  int* hF = rF + 128;
  const unsigned short* xpz = xpzr + (size_t)(d*2 + 0)*SBH;
  const unsigned short* xpr = xpzr + (size_t)(d*2 + 1)*SBH;
  const float*          xpd = xph  + (size_t)d*SBH;
  const unsigned short* xp1 = (p1g == 0) ? xpz : xpr;

  int budget = 1 << 21;
  __syncthreads();

  // wave-0-only ballot poll; others park at the barrier.
  #define WAIT_FLAGS(F, TGT)                                              \
    if (wv == 0){                                                         \
      for (;;){                                                           \
        bool ok = (lane < 16) ? (ld_ag_i32(&(F)[lane]) >= (TGT)) : true;  \
        if (__all(ok)) break;                                             \
        if (--budget <= 0) break;                                         \
        __builtin_amdgcn_s_sleep(1);                                      \
      }                                                                   \
      if (lane == 0 && budget <= 0) gvL = 1;                              \
    }                                                                     \
    __syncthreads();                                                      \
    if (gvL) return;

  for (int t = 0; t < 512; ++t){
    const int idx = (layer == 0 && d == 1) ? (511 - t) : t;
    const size_t xbase = (size_t)idx * 32768;

    // ---- prefetch this step's xp (latency hides under the poll) ----
    unsigned short xr1[16];
    #pragma unroll
    for (int m = 0; m < 4; ++m)
      #pragma unroll
      for (int i = 0; i < 4; ++i)
        xr1[m*4+i] = xp1[xbase + (size_t)(m*16 + l4*4 + i)*512 + myj];
    float xh[8];
    #pragma unroll
    for (int m = 0; m < 2; ++m)
      #pragma unroll
      for (int i = 0; i < 4; ++i)
        xh[m*4+i] = xpd[xbase + (size_t)(((wv>>1)*2+m)*16 + l4*4 + i)*512 + myj];

    // ---- wait h(t) ready (h(0) is memset) ----
    if (t > 0){ WAIT_FLAGS(hF, t) }

    // ---- stage h(t) -> hst: 32 u64/thread, staggered, swizzled ----
    {
      const u64* src = (const u64*)hpub_d;   // 8192 u64 = [64][512] bf16
      u64 v[32];
      #pragma unroll
      for (int j = 0; j < 32; ++j){
        int jj = (j + g*2) & 31;
        v[j] = ld_ag_u64(src + jj*256 + tid);
      }
      vm0();
      #pragma unroll
      for (int j = 0; j < 32; ++j){
        int jj = (j + g*2) & 31;
        int byte = (jj*256 + tid) * 8;
        *(u64*)((char*)hst + swz(byte)) = v[j];
      }
    }
    __syncthreads();

    // ---- P1: preact = h @ Wh{z|r}^T, 4 m-blocks per wave ----
    f32x4 acc[4];
    #pragma unroll
    for (int m = 0; m < 4; ++m) acc[m] = (f32x4){0.f,0.f,0.f,0.f};
    #pragma unroll
    for (int k0 = 0; k0 < 16; ++k0){
      #pragma unroll
      for (int m = 0; m < 4; ++m){
        int byte = (m*16 + l15)*1024 + k0*64 + l4*16;
        bf16x8 a = *(const bf16x8*)((const char*)hst + swz(byte));
        acc[m] = __builtin_amdgcn_mfma_f32_16x16x32_bf16(a, wf1[k0], acc[m], 0,0,0);
      }
    }
    if (p1g == 0){  // z waves
      #pragma unroll
      for (int m = 0; m < 4; ++m)
        #pragma unroll
        for (int i = 0; i < 4; ++i){
          int b = m*16 + l4*4 + i;
          float pre = acc[m][i] + b2f(xr1[m*4+i]);
          zL[b][jcl] = 1.f/(1.f + __expf(-pre));
        }
    } else {        // r waves: rh = r*h, publish packed hi|lo
      #pragma unroll
      for (int m = 0; m < 4; ++m)
        #pragma unroll
        for (int i = 0; i < 4; ++i){
          int b = m*16 + l4*4 + i;
          float pre = acc[m][i] + b2f(xr1[m*4+i]);
          float r = 1.f/(1.f + __expf(-pre));
          float rhv = r * h32[b][jcl];
          unsigned short hi = f2b(rhv);
          unsigned short lo = f2b(rhv - b2f(hi));
          st_ag_u32(rhp_d + (size_t)b*512 + myj, (unsigned int)hi | ((unsigned int)lo << 16));
        }
    }
    vm0();
    __syncthreads();
    if (tid == 0) st_ag_i32(&rF[g], t + 1);

    // ---- wait all rh(t) ----
    WAIT_FLAGS(rF, t + 1)

    // ---- stage rh -> hst(hi) + rhL(lo): 2 batches of 32 u64/thread ----
    {
      const u64* rsrc = (const u64*)rhp_d;   // 16384 u64 = [64][512] u32
      #pragma unroll
      for (int q = 0; q < 2; ++q){
        u64 v[32];
        #pragma unroll
        for (int j = 0; j < 32; ++j){
          int jj = (q*32 + ((j + g*4) & 31));
          v[j] = ld_ag_u64(rsrc + jj*256 + tid);
        }
        vm0();
        #pragma unroll
        for (int j = 0; j < 32; ++j){
          int jj = (q*32 + ((j + g*4) & 31));
          int gu = jj*256 + tid;                 // element-pair index
          unsigned int x0 = (unsigned int)v[j], x1 = (unsigned int)(v[j] >> 32);
          unsigned int hi = (x0 & 0xffffu) | (x1 << 16);
          unsigned int lo = (x0 >> 16) | (x1 & 0xffff0000u);
          int byte = (gu >> 8)*1024 + (gu & 255)*4;
          int ba = swz(byte);
          *(unsigned int*)((char*)hst + ba) = hi;
          *(unsigned int*)((char*)rhL + ba) = lo;
        }
      }
    }
    __syncthreads();

    // ---- P2: h~ = tanh(xph + rh @ Whh^T), 3-term split, 2 m-blocks ----
    f32x4 acc2[2];
    acc2[0] = (f32x4){0.f,0.f,0.f,0.f};
    acc2[1] = (f32x4){0.f,0.f,0.f,0.f};
    #pragma unroll
    for (int k0 = 0; k0 < 16; ++k0){
      #pragma unroll
      for (int m = 0; m < 2; ++m){
        int mb = (wv >> 1)*2 + m;
        int byte = (mb*16 + l15)*1024 + k0*64 + l4*16;
        int ba = swz(byte);
        bf16x8 ahi = *(const bf16x8*)((const char*)hst + ba);
        bf16x8 alo = *(const bf16x8*)((const char*)rhL + ba);
        acc2[m] = __builtin_amdgcn_mfma_f32_16x16x32_bf16(ahi, wf2[k0], acc2[m], 0,0,0);
        acc2[m] = __builtin_amdgcn_mfma_f32_16x16x32_bf16(alo, wf2[k0], acc2[m], 0,0,0);
        acc2[m] = __builtin_amdgcn_mfma_f32_16x16x32_bf16(ahi, wlo[k0], acc2[m], 0,0,0);
      }
    }
    #pragma unroll
    for (int m = 0; m < 2; ++m){
      #pragma unroll
      for (int i = 0; i < 4; ++i){
        int b = ((wv >> 1)*2 + m)*16 + l4*4 + i;
        float pre = acc2[m][i] + xh[m*4+i];
        float e  = __expf(-2.f*fabsf(pre));
        float th = (1.f - e)/(1.f + e);
        th = (pre < 0.f) ? -th : th;
        float z    = zL[b][jcl];
        float hold = h32[b][jcl];
        bool  msk  = (t < lenL[b]);
        float hn   = msk ? (hold + z*(th - hold)) : hold;
        h32[b][jcl] = hn;
        if (layer == 0){
          h0buf[(size_t)d*SBH + ((size_t)t*64 + b)*512 + myj] = f2b(hn);
        } else {
          int sout = d ? (511 - t) : t;
          out[((size_t)b*512 + sout)*1024 + (size_t)d*512 + myj] = msk ? hn : 0.f;
        }
      }
    }
    __syncthreads();   // h32 complete before publish reads

    // ---- publish h(t+1): each thread packs 8 cols (2 u64) of own 32 ----
    {
      int b = tid >> 2, c8 = (tid & 3)*8;
      unsigned short pk[8];
      #pragma unroll
      for (int j = 0; j < 8; ++j) pk[j] = f2b(h32[b][c8 + j]);
      u64 w0, w1;
      __builtin_memcpy(&w0, pk, 8);
      __builtin_memcpy(&w1, pk + 4, 8);
      u64* dst = (u64*)(hpub_d + (size_t)b*512 + colg0 + c8);
      st_ag_u64(dst + 0, w0);
      st_ag_u64(dst + 1, w1);
    }
    vm0();
    __syncthreads();
    if (tid == 0) st_ag_i32(&hF[g], t + 1);
  }
  #undef WAIT_FLAGS
}

// ---------------- host launcher ----------------
extern "C" void kernel_launch(void* const* d_in, const int* in_sizes, int n_in,
                              void* d_out, int out_size, void* d_ws, size_t ws_size,
                              hipStream_t stream)
{
  const int*   tokens  = (const int*)  d_in[0];
  const int*   lengths = (const int*)  d_in[1];
  const float* table   = (const float*)d_in[2];
  const float* Wxz = (const float*)d_in[3];
  const float* bxz = (const float*)d_in[4];
  const float* Whz = (const float*)d_in[5];
  const float* Wxr = (const float*)d_in[6];
  const float* bxr = (const float*)d_in[7];
  const float* Whr = (const float*)d_in[8];
  const float* Wxh = (const float*)d_in[9];
  const float* bxh = (const float*)d_in[10];
  const float* Whh = (const float*)d_in[11];
  float* out = (float*)d_out;

  char* ws = (char*)d_ws;
  if (ws_size < WS_TOTAL){
    sentinel_kernel<<<1, 1, 0, stream>>>(out);
    return;
  }
  unsigned short* hpub = (unsigned short*)(ws + OFF_HPUB);
  unsigned int*   rhp  = (unsigned int*)  (ws + OFF_RHP);
  int*            flags= (int*)           (ws + OFF_FLAGS);
  unsigned short* xpzr = (unsigned short*)(ws + OFF_XPZR);
  float*          xph  = (float*)         (ws + OFF_XPH);
  unsigned short* h0   = (unsigned short*)(ws + OFF_H0);
  unsigned short* wbf  = (unsigned short*)(ws + OFF_WBF);

  hipMemsetAsync(ws, 0, CTRL_BYTES, stream);
  convert_kernel<<<dim3(1024, 6), 256, 0, stream>>>(Wxz, Wxr, Wxh, Whz, Whr, Whh, wbf);

  // layer 0
  xproj_kernel<<<dim3(256, 8, 6), 256, 0, stream>>>(0, tokens, table, h0, wbf,
                                                    bxz, bxr, bxh, xpzr, xph);
  recur_kernel<<<dim3(32), 256, 0, stream>>>(0, xpzr, xph, wbf, Whh, h0, out,
                                             lengths, hpub, rhp, flags);
  // layer 1
  hipMemsetAsync(ws, 0, CTRL_BYTES, stream);
  xproj_kernel<<<dim3(256, 8, 6), 256, 0, stream>>>(1, tokens, table, h0, wbf,
                                                    bxz, bxr, bxh, xpzr, xph);
  recur_kernel<<<dim3(32), 256, 0, stream>>>(1, xpzr, xph, wbf, Whh, h0, out,
                                             lengths, hpub, rhp, flags);
}